// Round 5
// baseline (572.894 us; speedup 1.0000x reference)
//
#include <hip/hip_runtime.h>

// LSTM: B=32768, T=28, D=28, H=8, gates=32, classes=10.
//
// Mapping (hardware-verified in R2): 32 lanes per batch element; lane
// l5=(tid&31) owns ONE gate column l5 of W[36][32] (col order i|j|f|o ->
// column index == lane index). 36 W VGPRs, pinned resident.
//
// R2 lesson (VGPR=56): compiler sank the x-prefetch loads to the top of
// each step and waited immediately -> ~400-900cy exposed latency/step.
// R3 lesson (NaN): hand-asm global_load + manual vmcnt is unverifiable;
// one under-wait poisons the recurrent c. Abandoned.
// R4: container infra failure (no kernel verdict) -> resubmit with the
// pin applied per-component (removes the one untested asm construct,
// 128-bit "v" operands; loads stay float4 so dwordx4 is preserved).
//
// This version: COMPILER-MANAGED loads, placement-controlled:
//   top of step:  issue 7 plain float4 loads for x[t+1]   (no use -> no wait)
//   sched_barrier(0)                                      (loads can't sink)
//   STEP on current buffer (R2's verified body)
//   sched_barrier(0)
//   PIN next buffer (asm "+v")  <- SIInsertWaitcnts puts the vmcnt wait HERE,
//                                  after the FMAs; pin also keeps the 28 regs
//                                  loop-carried (proven mechanism from W pin).
// Everything is plain C + empty asm: correctness compiler-guaranteed.
//
// Cross-lane exchange: BitMode ds_swizzle imms verified on HW in R2.
// Activation lane-uniform via constants:
//   a = qK + mK * rcp(1 + exp2(sK*z)); i,f,o sigmoid; j tanh; forget bias
//   folded into bg for gt==2.
//
// Regs ~120: 36 W + 2x28 x + 8 h + ~20 misc -> 4 waves/SIMD (cap 128).
// 4096 blocks x 256 threads = 16384 waves.

#define TSTEPS 28
#define DIN    28
#define NH     8
#define NG     32
#define NC     10
#define NROWS  36

__device__ __forceinline__ float fexp2(float x) { return __builtin_amdgcn_exp2f(x); }
__device__ __forceinline__ float frcp(float x)  { return __builtin_amdgcn_rcpf(x); }

#define SWZ(v, imm) \
    __int_as_float(__builtin_amdgcn_ds_swizzle(__float_as_int(v), (imm)))
#define SB() __builtin_amdgcn_sched_barrier(0)
// Pin a float4 component-wise: ties each scalar VGPR without requiring a
// 128-bit asm operand. Loads are still issued as float4 (dwordx4).
#define PIN4(v) do {                         \
    asm volatile("" : "+v"((v).x));          \
    asm volatile("" : "+v"((v).y));          \
    asm volatile("" : "+v"((v).z));          \
    asm volatile("" : "+v"((v).w));          \
} while (0)

__global__ __launch_bounds__(256, 4) void lstm_kernel(
    const float* __restrict__ x,      // [B, T, D]
    const float* __restrict__ W,      // [36, 32]  col order i,j,f,o
    const float* __restrict__ bias,   // [32]
    const float* __restrict__ Wout,   // [8, 10]
    const float* __restrict__ bout,   // [10]
    float* __restrict__ out)          // [B, 10]
{
    const int tid = blockIdx.x * 256 + threadIdx.x;
    const int e   = tid >> 5;             // batch element (32 lanes each)
    const int l5  = threadIdx.x & 31;     // gate column owned by this lane
    const int gt  = l5 >> 3;              // gate type 0..3 = i,j,f,o

    const float* xb = x + (size_t)e * (TSTEPS * DIN);

    // Preload + pin this lane's gate column of W (36 VGPRs).
    float Wr[NROWS];
#pragma unroll
    for (int k = 0; k < NROWS; ++k) Wr[k] = W[k * NG + l5];
#pragma unroll
    for (int k = 0; k < NROWS; ++k) asm volatile("" : "+v"(Wr[k]));

    const float bg = bias[l5] + (gt == 2 ? 1.0f : 0.0f);     // forget bias
    const float sK = (gt == 1) ?  2.8853900817779268f : -1.4426950408889634f;
    const float mK = (gt == 1) ? -2.0f : 1.0f;
    const float qK = (gt == 1) ?  1.0f : 0.0f;

    float c = 0.0f;
    float hall[NH];
#pragma unroll
    for (int j = 0; j < NH; ++j) hall[j] = 0.0f;

    // x double-buffer: A holds current step, B the prefetch (and swap).
    float4 xA[7], xB[7];
    {
        const float4* xv = (const float4*)xb;
#pragma unroll
        for (int i = 0; i < 7; ++i) xA[i] = xv[i];
#pragma unroll
        for (int i = 0; i < 7; ++i) PIN4(xA[i]);
    }

    // R2's hardware-verified step body (4 accumulator chains, BitMode
    // swizzle gathers/broadcasts for 32-lane groups).
#define STEP(XQ)                                                          \
    do {                                                                  \
        float g0 = bg, g1 = 0.0f, g2 = 0.0f, g3 = 0.0f;                   \
        _Pragma("unroll")                                                 \
        for (int i = 0; i < 7; ++i) {                                     \
            g0 = fmaf(XQ[i].x, Wr[4*i+0], g0);                            \
            g1 = fmaf(XQ[i].y, Wr[4*i+1], g1);                            \
            g2 = fmaf(XQ[i].z, Wr[4*i+2], g2);                            \
            g3 = fmaf(XQ[i].w, Wr[4*i+3], g3);                            \
        }                                                                 \
        _Pragma("unroll")                                                 \
        for (int k = 0; k < NH; k += 4) {                                 \
            g0 = fmaf(hall[k+0], Wr[DIN+k+0], g0);                        \
            g1 = fmaf(hall[k+1], Wr[DIN+k+1], g1);                        \
            g2 = fmaf(hall[k+2], Wr[DIN+k+2], g2);                        \
            g3 = fmaf(hall[k+3], Wr[DIN+k+3], g3);                        \
        }                                                                 \
        float g = (g0 + g1) + (g2 + g3);                                  \
        float a = fmaf(mK, frcp(1.0f + fexp2(sK * g)), qK);               \
        float iv = SWZ(a, 0x0007);                                        \
        float jv = SWZ(a, 0x0107);                                        \
        float fv = SWZ(a, 0x0207);                                        \
        float ov = SWZ(a, 0x0307);                                        \
        c = fmaf(c, fv, iv * jv);                                         \
        float th = fmaf(-2.0f,                                            \
                        frcp(1.0f + fexp2(2.8853900817779268f * c)),      \
                        1.0f);                                            \
        float hu = th * ov;                                               \
        hall[0] = SWZ(hu, 0x0000);                                        \
        hall[1] = SWZ(hu, 0x0020);                                        \
        hall[2] = SWZ(hu, 0x0040);                                        \
        hall[3] = SWZ(hu, 0x0060);                                        \
        hall[4] = SWZ(hu, 0x0080);                                        \
        hall[5] = SWZ(hu, 0x00A0);                                        \
        hall[6] = SWZ(hu, 0x00C0);                                        \
        hall[7] = SWZ(hu, 0x00E0);                                        \
    } while (0)

#pragma unroll 1
    for (int t = 0; t < TSTEPS; t += 2) {
        // issue x[t+1] loads (plain C; no use yet -> no wait here)
        {
            const float4* xv = (const float4*)(xb + (t + 1) * DIN);
#pragma unroll
            for (int i = 0; i < 7; ++i) xB[i] = xv[i];
        }
        SB();                 // loads may not sink below this point
        STEP(xA);
        SB();
#pragma unroll
        for (int i = 0; i < 7; ++i) PIN4(xB[i]);   // vmcnt wait lands here

        // issue x[t+2] loads (clamped; last pair's reload is dead but valid)
        {
            const int tn = (t + 2 < TSTEPS) ? (t + 2) : (TSTEPS - 1);
            const float4* xv = (const float4*)(xb + tn * DIN);
#pragma unroll
            for (int i = 0; i < 7; ++i) xA[i] = xv[i];
        }
        SB();
        STEP(xB);
        SB();
#pragma unroll
        for (int i = 0; i < 7; ++i) PIN4(xA[i]);
    }

    // logits = h @ Wout + bout; lanes 0..9 of each group write one column.
    if (l5 < NC) {
        float acc = bout[l5];
#pragma unroll
        for (int k = 0; k < NH; ++k)
            acc = fmaf(hall[k], Wout[k * NC + l5], acc);
        out[(size_t)e * NC + l5] = acc;
    }
}

extern "C" void kernel_launch(void* const* d_in, const int* in_sizes, int n_in,
                              void* d_out, int out_size, void* d_ws, size_t ws_size,
                              hipStream_t stream) {
    const float* x    = (const float*)d_in[0];
    const float* W    = (const float*)d_in[1];
    const float* b    = (const float*)d_in[2];
    const float* Wout = (const float*)d_in[3];
    const float* bout = (const float*)d_in[4];
    float* out = (float*)d_out;

    const int B = in_sizes[0] / (TSTEPS * DIN);  // 32768
    const int threads = B * NG;                  // 32 lanes per element
    const int block = 256;
    const int grid = threads / block;            // 4096
    lstm_kernel<<<grid, block, 0, stream>>>(x, W, b, Wout, bout, out);
}

// Round 6
// 185.446 us; speedup vs baseline: 3.0893x; 3.0893x over previous
//
#include <hip/hip_runtime.h>

// LSTM: B=32768, T=28, D=28, H=8, gates=32, classes=10.
//
// Mapping (hardware-verified R2): 32 lanes per batch element; lane
// l5=(tid&31) owns ONE gate column l5 of W[36][32] (col order i|j|f|o ->
// column index == lane index). 36 W VGPRs, pinned (the pin that WORKED).
//
// History of the x-feed (the whole game on this kernel):
//   R2: compiler sank x prefetch (VGPR=56) -> ~143us, exposed global latency.
//   R3: hand-asm loads + manual vmcnt -> NaN. Abandoned.
//   R5: pinned reg double-buffer -> allocator chose 64-reg tier and SPILLED
//       the pinned buffers (WRITE_SIZE 157MB, FETCH 825MB, 466us).
//   Conclusion: ~60 loop-carried global-load regs are unkeepable; the
//   scheduler always trades them for occupancy (sink or spill).
//
// This version: x lives in LDS. A block's 8 elements need 8*28*28*4 = 25KB
// -> stage ONCE, coalesced, in the prologue; the t-loop has ZERO global
// loads. Per step: 7 ds_read_b128, broadcast (all 32 lanes of a group read
// the same address -> conflict-free; the wave's two groups are 3136B apart
// = bank offset 16 -> disjoint bank quads). Worst-case compiler placement
// costs ~120cy LDS latency per step, not 400-900cy HBM.
//
// Step body = R2's verified math: 4 accumulator chains, lane-uniform
// activation a = qK + mK*rcp(1+exp2(sK*z)) (i,f,o sigmoid; j tanh; forget
// bias folded), BitMode ds_swizzle gathers/broadcasts. x-part (pure ILP,
// no recurrence) computed before h-part so unroll-2 overlaps t+1's x-FMAs
// with t's serial swizzle/activation chain.
//
// Budget: 36 W + 28 xq + 8 h + ~20 misc ~= 92 VGPR; LDS 25088B -> 6
// blocks/CU. 4096 blocks x 256 threads = 16384 waves.

#define TSTEPS 28
#define DIN    28
#define NH     8
#define NG     32
#define NC     10
#define NROWS  36
#define EPB    8                       // elements per block
#define XQ_PER_ELEM (TSTEPS * 7)       // 196 float4 per element

__device__ __forceinline__ float fexp2(float x) { return __builtin_amdgcn_exp2f(x); }
__device__ __forceinline__ float frcp(float x)  { return __builtin_amdgcn_rcpf(x); }

#define SWZ(v, imm) \
    __int_as_float(__builtin_amdgcn_ds_swizzle(__float_as_int(v), (imm)))

__global__ __launch_bounds__(256, 4) void lstm_kernel(
    const float* __restrict__ x,      // [B, T, D]
    const float* __restrict__ W,      // [36, 32]  col order i,j,f,o
    const float* __restrict__ bias,   // [32]
    const float* __restrict__ Wout,   // [8, 10]
    const float* __restrict__ bout,   // [10]
    float* __restrict__ out)          // [B, 10]
{
    __shared__ float4 xs[EPB * XQ_PER_ELEM];   // 25088 B

    const int g   = threadIdx.x >> 5;          // element group in block (0..7)
    const int l5  = threadIdx.x & 31;          // gate column owned by lane
    const int gt  = l5 >> 3;                   // gate type 0..3 = i,j,f,o
    const int e   = blockIdx.x * EPB + g;      // batch element

    // ---- Stage the block's entire x into LDS (coalesced float4) ----
    {
        const float4* gx = (const float4*)(x + (size_t)blockIdx.x *
                                           (EPB * TSTEPS * DIN));
#pragma unroll
        for (int i = 0; i < 7; ++i) {
            int idx = threadIdx.x + i * 256;
            if (idx < EPB * XQ_PER_ELEM) xs[idx] = gx[idx];
        }
    }

    // ---- Preload + pin this lane's gate column of W (36 VGPRs) ----
    float Wr[NROWS];
#pragma unroll
    for (int k = 0; k < NROWS; ++k) Wr[k] = W[k * NG + l5];
#pragma unroll
    for (int k = 0; k < NROWS; ++k) asm volatile("" : "+v"(Wr[k]));

    const float bg = bias[l5] + (gt == 2 ? 1.0f : 0.0f);     // forget bias
    const float sK = (gt == 1) ?  2.8853900817779268f : -1.4426950408889634f;
    const float mK = (gt == 1) ? -2.0f : 1.0f;
    const float qK = (gt == 1) ?  1.0f : 0.0f;

    float c = 0.0f;
    float hall[NH];
#pragma unroll
    for (int j = 0; j < NH; ++j) hall[j] = 0.0f;

    __syncthreads();

    const float4* xrow = xs + g * XQ_PER_ELEM;

#pragma unroll 2
    for (int t = 0; t < TSTEPS; ++t) {
        // 7 broadcast ds_read_b128 (all 32 lanes of the group: same addr)
        float4 xq[7];
#pragma unroll
        for (int i = 0; i < 7; ++i) xq[i] = xrow[t * 7 + i];

        // x-part: 28 FMAs, 4 independent chains, no recurrence dependency.
        float g0 = bg, g1 = 0.0f, g2 = 0.0f, g3 = 0.0f;
#pragma unroll
        for (int i = 0; i < 7; ++i) {
            g0 = fmaf(xq[i].x, Wr[4*i+0], g0);
            g1 = fmaf(xq[i].y, Wr[4*i+1], g1);
            g2 = fmaf(xq[i].z, Wr[4*i+2], g2);
            g3 = fmaf(xq[i].w, Wr[4*i+3], g3);
        }
        // h-part: 8 FMAs (depends on previous step's broadcast h)
#pragma unroll
        for (int k = 0; k < NH; k += 4) {
            g0 = fmaf(hall[k+0], Wr[DIN+k+0], g0);
            g1 = fmaf(hall[k+1], Wr[DIN+k+1], g1);
            g2 = fmaf(hall[k+2], Wr[DIN+k+2], g2);
            g3 = fmaf(hall[k+3], Wr[DIN+k+3], g3);
        }
        float gsum = (g0 + g1) + (g2 + g3);

        // Lane-uniform activation: sigmoid (i,f,o) / tanh (j).
        float a = fmaf(mK, frcp(1.0f + fexp2(sK * gsum)), qK);

        // Gather the four activated gates of this lane's unit u = l5&7.
        float iv = SWZ(a, 0x0007);
        float jv = SWZ(a, 0x0107);
        float fv = SWZ(a, 0x0207);
        float ov = SWZ(a, 0x0307);

        // Cell update (replicated across the unit's 4 gate-lanes).
        c = fmaf(c, fv, iv * jv);
        float th = fmaf(-2.0f,
                        frcp(1.0f + fexp2(2.8853900817779268f * c)),
                        1.0f);
        float hu = th * ov;

        // Broadcast h of units 0..7 across the 32-lane group.
        hall[0] = SWZ(hu, 0x0000);
        hall[1] = SWZ(hu, 0x0020);
        hall[2] = SWZ(hu, 0x0040);
        hall[3] = SWZ(hu, 0x0060);
        hall[4] = SWZ(hu, 0x0080);
        hall[5] = SWZ(hu, 0x00A0);
        hall[6] = SWZ(hu, 0x00C0);
        hall[7] = SWZ(hu, 0x00E0);
    }

    // logits = h @ Wout + bout; lanes 0..9 of each group write one column.
    if (l5 < NC) {
        float acc = bout[l5];
#pragma unroll
        for (int k = 0; k < NH; ++k)
            acc = fmaf(hall[k], Wout[k * NC + l5], acc);
        out[(size_t)e * NC + l5] = acc;
    }
}

extern "C" void kernel_launch(void* const* d_in, const int* in_sizes, int n_in,
                              void* d_out, int out_size, void* d_ws, size_t ws_size,
                              hipStream_t stream) {
    const float* x    = (const float*)d_in[0];
    const float* W    = (const float*)d_in[1];
    const float* b    = (const float*)d_in[2];
    const float* Wout = (const float*)d_in[3];
    const float* bout = (const float*)d_in[4];
    float* out = (float*)d_out;

    const int B = in_sizes[0] / (TSTEPS * DIN);  // 32768
    const int grid = B / EPB;                    // 4096 blocks
    lstm_kernel<<<grid, 256, 0, stream>>>(x, W, b, Wout, bout, out);
}

// Round 9
// 182.659 us; speedup vs baseline: 3.1364x; 1.0153x over previous
//
#include <hip/hip_runtime.h>

// LSTM: B=32768, T=28, D=28, H=8, gates=32, classes=10.
//
// Mapping (hardware-verified R2/R6): 32 lanes per batch element; lane
// l5=(tid&31) owns ONE gate column l5 of W[36][32] (col order i|j|f|o ->
// column index == lane index).
//
// R6 state: x staged in LDS (25KB/block, zero in-loop global loads),
// 77.7us, VALUBusy 60%, Occupancy 47%, VGPR 44, no spill. Bottleneck:
// per-step critical path had TWO serial LDS swizzle rounds (~120cy each).
//
// R8 lesson (absmax 0.484): DPP row_ror:1 direction was inverted in my
// weight pairing. AMD convention (cf. the canonical row_shr prefix-sum
// idiom): rotate-RIGHT moves DATA toward higher lanes, so dst lane p
// reads src lane (p-1)%16. After s hops lane p holds h_{(p-s)&7}.
// Fix: Wh[s] = W[DIN + ((u - s) & 7)][l5]  (was (u+s)&7).
//
// Structure (R7):
//  1. h-broadcast LDS round replaced by DPP row_ror:1 rotation chain
//     (~4cy/hop vs ~120cy LDS round; -8 LDS issues/step). Each 16-lane
//     row holds h0..h7 twice (lane pos p -> unit p&7); 16 = 0 mod 8 so
//     rotation never breaks the unit period. hall[] rebuilt once after
//     the loop (R2-verified broadcast imms) for the logits epilogue.
//  2. __launch_bounds__(256,6): LDS admits 6 blocks/CU (150KB/160KB).
//     Revert trigger: WRITE_SIZE > 1280KB (spill).
//
// Budget: 28 Wx + 8 Wh pinned = 36; peak ~80 VGPR. 4096 blocks x 256.

#define TSTEPS 28
#define DIN    28
#define NH     8
#define NG     32
#define NC     10
#define EPB    8                       // elements per block
#define XQ_PER_ELEM (TSTEPS * 7)       // 196 float4 per element

__device__ __forceinline__ float fexp2(float x) { return __builtin_amdgcn_exp2f(x); }
__device__ __forceinline__ float frcp(float x)  { return __builtin_amdgcn_rcpf(x); }

#define SWZ(v, imm) \
    __int_as_float(__builtin_amdgcn_ds_swizzle(__float_as_int(v), (imm)))

// DPP row_ror:1 (ctrl 0x121): DATA rotates toward higher lanes;
// dst lane p reads src lane (p-1)%16. All src lanes valid -> bound_ctrl
// irrelevant for rotation.
__device__ __forceinline__ float dpp_ror1(float v) {
    int i = __float_as_int(v);
    return __int_as_float(
        __builtin_amdgcn_update_dpp(i, i, 0x121, 0xF, 0xF, true));
}

__global__ __launch_bounds__(256, 6) void lstm_kernel(
    const float* __restrict__ x,      // [B, T, D]
    const float* __restrict__ W,      // [36, 32]  col order i,j,f,o
    const float* __restrict__ bias,   // [32]
    const float* __restrict__ Wout,   // [8, 10]
    const float* __restrict__ bout,   // [10]
    float* __restrict__ out)          // [B, 10]
{
    __shared__ float4 xs[EPB * XQ_PER_ELEM];   // 25088 B

    const int g   = threadIdx.x >> 5;          // element group in block (0..7)
    const int l5  = threadIdx.x & 31;          // gate column owned by lane
    const int u   = l5 & 7;                    // hidden unit of this column
    const int gt  = l5 >> 3;                   // gate type 0..3 = i,j,f,o
    const int e   = blockIdx.x * EPB + g;      // batch element

    // ---- Stage the block's entire x into LDS (coalesced float4) ----
    {
        const float4* gx = (const float4*)(x + (size_t)blockIdx.x *
                                           (EPB * TSTEPS * DIN));
#pragma unroll
        for (int i = 0; i < 7; ++i) {
            int idx = threadIdx.x + i * 256;
            if (idx < EPB * XQ_PER_ELEM) xs[idx] = gx[idx];
        }
    }

    // ---- Preload + pin weights (36 VGPRs) ----
    // x-part: natural order. h-part: ROTATION order matching row_ror:1
    // direction: after s hops this lane holds h_{(u-s)&7}.
    float Wx[DIN];
#pragma unroll
    for (int k = 0; k < DIN; ++k) Wx[k] = W[k * NG + l5];
    float Wh[NH];
#pragma unroll
    for (int s = 0; s < NH; ++s)
        Wh[s] = W[(DIN + ((u - s + 8) & 7)) * NG + l5];
#pragma unroll
    for (int k = 0; k < DIN; ++k) asm volatile("" : "+v"(Wx[k]));
#pragma unroll
    for (int s = 0; s < NH; ++s) asm volatile("" : "+v"(Wh[s]));

    const float bg = bias[l5] + (gt == 2 ? 1.0f : 0.0f);     // forget bias
    const float sK = (gt == 1) ?  2.8853900817779268f : -1.4426950408889634f;
    const float mK = (gt == 1) ? -2.0f : 1.0f;
    const float qK = (gt == 1) ?  1.0f : 0.0f;

    float c = 0.0f;
    float hprev = 0.0f;                // this unit's h (replicated x4 gates)

    __syncthreads();

    const float4* xrow = xs + g * XQ_PER_ELEM;

#pragma unroll 2
    for (int t = 0; t < TSTEPS; ++t) {
        // 7 broadcast ds_read_b128 (all 32 lanes of the group: same addr)
        float4 xq[7];
#pragma unroll
        for (int i = 0; i < 7; ++i) xq[i] = xrow[t * 7 + i];

        // x-part: 28 FMAs, 4 independent chains (no recurrence dep).
        float g0 = bg, g1 = 0.0f, g2 = 0.0f, g3 = 0.0f;
#pragma unroll
        for (int i = 0; i < 7; ++i) {
            g0 = fmaf(xq[i].x, Wx[4*i+0], g0);
            g1 = fmaf(xq[i].y, Wx[4*i+1], g1);
            g2 = fmaf(xq[i].z, Wx[4*i+2], g2);
            g3 = fmaf(xq[i].w, Wx[4*i+3], g3);
        }

        // h-part: DPP rotation chain, 8 hops; hop s delivers h_{(u-s)&7},
        // matched with Wh[s]. Replaces the 8 LDS broadcast swizzles.
        {
            float hc = hprev;
            g0 = fmaf(hc, Wh[0], g0);
            hc = dpp_ror1(hc); g1 = fmaf(hc, Wh[1], g1);
            hc = dpp_ror1(hc); g2 = fmaf(hc, Wh[2], g2);
            hc = dpp_ror1(hc); g3 = fmaf(hc, Wh[3], g3);
            hc = dpp_ror1(hc); g0 = fmaf(hc, Wh[4], g0);
            hc = dpp_ror1(hc); g1 = fmaf(hc, Wh[5], g1);
            hc = dpp_ror1(hc); g2 = fmaf(hc, Wh[6], g2);
            hc = dpp_ror1(hc); g3 = fmaf(hc, Wh[7], g3);
        }
        float gsum = (g0 + g1) + (g2 + g3);

        // Lane-uniform activation: sigmoid (i,f,o) / tanh (j).
        float a = fmaf(mK, frcp(1.0f + fexp2(sK * gsum)), qK);

        // Gather the four activated gates of unit u (R2-verified imms).
        float iv = SWZ(a, 0x0007);
        float jv = SWZ(a, 0x0107);
        float fv = SWZ(a, 0x0207);
        float ov = SWZ(a, 0x0307);

        // Cell update (replicated across the unit's 4 gate-lanes).
        c = fmaf(c, fv, iv * jv);
        float th = fmaf(-2.0f,
                        frcp(1.0f + fexp2(2.8853900817779268f * c)),
                        1.0f);
        hprev = th * ov;
    }

    // Rebuild hall[0..7] once (R2-verified broadcast imms), then logits.
    float hall[NH];
    hall[0] = SWZ(hprev, 0x0000);
    hall[1] = SWZ(hprev, 0x0020);
    hall[2] = SWZ(hprev, 0x0040);
    hall[3] = SWZ(hprev, 0x0060);
    hall[4] = SWZ(hprev, 0x0080);
    hall[5] = SWZ(hprev, 0x00A0);
    hall[6] = SWZ(hprev, 0x00C0);
    hall[7] = SWZ(hprev, 0x00E0);

    if (l5 < NC) {
        float acc = bout[l5];
#pragma unroll
        for (int k = 0; k < NH; ++k)
            acc = fmaf(hall[k], Wout[k * NC + l5], acc);
        out[(size_t)e * NC + l5] = acc;
    }
}

extern "C" void kernel_launch(void* const* d_in, const int* in_sizes, int n_in,
                              void* d_out, int out_size, void* d_ws, size_t ws_size,
                              hipStream_t stream) {
    const float* x    = (const float*)d_in[0];
    const float* W    = (const float*)d_in[1];
    const float* b    = (const float*)d_in[2];
    const float* Wout = (const float*)d_in[3];
    const float* bout = (const float*)d_in[4];
    float* out = (float*)d_out;

    const int B = in_sizes[0] / (TSTEPS * DIN);  // 32768
    const int grid = B / EPB;                    // 4096 blocks
    lstm_kernel<<<grid, 256, 0, stream>>>(x, W, b, Wout, bout, out);
}

// Round 10
// 182.541 us; speedup vs baseline: 3.1384x; 1.0006x over previous
//
#include <hip/hip_runtime.h>

// LSTM: B=32768, T=28, D=28, H=8, gates=32, classes=10.
//
// R9 diagnosis: LDS-return-BW bound. 7 broadcast ds_read_b128 per
// 32-lane-group step return 7KB (112B useful, 64x lane replication);
// at ~12cy/b128 (m134) -> 64 waves/CU x 28 x 84cy ~ 63us ~ measured 76.
// Removing 8 swizzles (R9 DPP chain) changed nothing -> reads dominate.
//
// R10: 16 lanes per element, 2 gate columns per lane. One wave = 4
// elements; ONE b128 with per-16-lane-group addresses feeds all 4
// elements -> LDS bytes per element-step drop 4x (7KB -> 1.75KB).
// Element rows padded to 788 floats so the 4 groups' reads start at
// banks {0,20,8,28} -> conflict-free 16-way broadcasts.
//
// Lane m (0..15) owns col_lo=m (i-gate for m<8, j for m>=8 of unit
// u=m&7) and col_hi=m+16 (f / o). Gate gather is now pure DPP:
//   partner = row_ror:8 (lane XOR 8 within the 16-lane row; involution
//   -> no direction bug possible).
//   iv*jv == a_lo * p_lo for BOTH lane halves (symmetric product, no
//   select); fv = m<8 ? a_hi : p_hi; ov = m<8 ? p_hi : a_hi (2 cndmask).
// h-broadcast chain: R9's HW-VERIFIED row_ror:1 + Wh[s]=W[DIN+((u-s)&7)]
// pairing, unchanged (16-lane group == one DPP row).
// Zero in-loop ds_swizzle; epilogue-only swizzle broadcast with and=0x10
// (keep bit4 -> stay within the 16-lane group).
//
// Budget: 72 pinned W + 28 xq + misc ~ 120 VGPR (cap 128 via
// __launch_bounds__(256,4)); LDS 50432B -> 3 blocks/CU (12 waves, 37%).
// VALU-issue bound ~210cy/wave-step -> ~20us ideal.
// Revert trigger: WRITE_SIZE > 1280KB (spill).

#define TSTEPS 28
#define DIN    28
#define NH     8
#define NG     32
#define NC     10
#define EPB    16                  // elements per block (256 thr / 16 lanes)
#define XF4    197                 // float4 per element row in LDS (196+1 pad)

__device__ __forceinline__ float fexp2(float x) { return __builtin_amdgcn_exp2f(x); }
__device__ __forceinline__ float frcp(float x)  { return __builtin_amdgcn_rcpf(x); }

#define SWZ(v, imm) \
    __int_as_float(__builtin_amdgcn_ds_swizzle(__float_as_int(v), (imm)))

// DPP row_ror:1 (ctrl 0x121): dst lane p reads src lane (p-1)%16.
// HW-verified in R9 with Wh[s] = W[DIN + ((u-s)&7)] pairing.
__device__ __forceinline__ float dpp_ror1(float v) {
    int i = __float_as_int(v);
    return __int_as_float(
        __builtin_amdgcn_update_dpp(i, i, 0x121, 0xF, 0xF, true));
}
// DPP row_ror:8 (ctrl 0x128): rotation by 8 on a 16-lane row == lane^8.
// Involution -> direction-proof.
__device__ __forceinline__ float dpp_xor8(float v) {
    int i = __float_as_int(v);
    return __int_as_float(
        __builtin_amdgcn_update_dpp(i, i, 0x128, 0xF, 0xF, true));
}

__global__ __launch_bounds__(256, 4) void lstm_kernel(
    const float* __restrict__ x,      // [B, T, D]
    const float* __restrict__ W,      // [36, 32]  col order i,j,f,o
    const float* __restrict__ bias,   // [32]
    const float* __restrict__ Wout,   // [8, 10]
    const float* __restrict__ bout,   // [10]
    float* __restrict__ out)          // [B, 10]
{
    __shared__ float4 xs[EPB * XF4];           // 50432 B

    const int  eb   = threadIdx.x >> 4;        // element within block (0..15)
    const int  m    = threadIdx.x & 15;        // lane within element group
    const int  u    = m & 7;                   // hidden unit
    const bool lowm = (m < 8);                 // owns i/f (else j/o)
    const int  e    = blockIdx.x * EPB + eb;   // batch element

    // ---- Stage x: global contiguous -> LDS with 788-float row stride ----
    {
        const float4* gx = (const float4*)(x + (size_t)blockIdx.x *
                                           (EPB * TSTEPS * DIN));
        for (int idx = threadIdx.x; idx < EPB * 196; idx += 256) {
            int el = idx / 196, r = idx - el * 196;
            xs[el * XF4 + r] = gx[idx];
        }
    }

    // ---- Preload + pin this lane's TWO gate columns (72 VGPRs) ----
    const int col_lo = m, col_hi = m + 16;
    float Wx0[DIN], Wx1[DIN];
#pragma unroll
    for (int k = 0; k < DIN; ++k) {
        Wx0[k] = W[k * NG + col_lo];
        Wx1[k] = W[k * NG + col_hi];
    }
    float Wh0[NH], Wh1[NH];
#pragma unroll
    for (int s = 0; s < NH; ++s) {
        int r = DIN + ((u - s + 8) & 7);       // R9-verified rotation order
        Wh0[s] = W[r * NG + col_lo];
        Wh1[s] = W[r * NG + col_hi];
    }
#pragma unroll
    for (int k = 0; k < DIN; ++k) {
        asm volatile("" : "+v"(Wx0[k]));
        asm volatile("" : "+v"(Wx1[k]));
    }
#pragma unroll
    for (int s = 0; s < NH; ++s) {
        asm volatile("" : "+v"(Wh0[s]));
        asm volatile("" : "+v"(Wh1[s]));
    }

    // lo column: i (sigmoid) for m<8, j (tanh) for m>=8.
    // hi column: f (sigmoid, +1 bias) for m<8, o (sigmoid) for m>=8.
    const float bg_lo = bias[col_lo];
    const float bg_hi = bias[col_hi] + (lowm ? 1.0f : 0.0f);
    const float sK = lowm ? -1.4426950408889634f :  2.8853900817779268f;
    const float mK = lowm ?  1.0f                : -2.0f;
    const float qK = lowm ?  0.0f                :  1.0f;

    float c = 0.0f;
    float hprev = 0.0f;            // h_u (replicated at lanes m and m^8)

    __syncthreads();

    const float4* xrow = xs + eb * XF4;

#pragma unroll 2
    for (int t = 0; t < TSTEPS; ++t) {
        // 7 ds_read_b128; 4 distinct addresses per wave (one per element
        // group), 16-way broadcast each, disjoint bank-quads.
        float4 xq[7];
#pragma unroll
        for (int i = 0; i < 7; ++i) xq[i] = xrow[t * 7 + i];

        // x-part: 56 FMAs (2 cols), 4 chains each.
        float g0 = bg_lo, g1 = 0.0f, g2 = 0.0f, g3 = 0.0f;
        float G0 = bg_hi, G1 = 0.0f, G2 = 0.0f, G3 = 0.0f;
#pragma unroll
        for (int i = 0; i < 7; ++i) {
            g0 = fmaf(xq[i].x, Wx0[4*i+0], g0);
            G0 = fmaf(xq[i].x, Wx1[4*i+0], G0);
            g1 = fmaf(xq[i].y, Wx0[4*i+1], g1);
            G1 = fmaf(xq[i].y, Wx1[4*i+1], G1);
            g2 = fmaf(xq[i].z, Wx0[4*i+2], g2);
            G2 = fmaf(xq[i].z, Wx1[4*i+2], G2);
            g3 = fmaf(xq[i].w, Wx0[4*i+3], g3);
            G3 = fmaf(xq[i].w, Wx1[4*i+3], G3);
        }

        // h-part: R9-verified DPP rotation chain; hop s delivers h_{(u-s)&7}.
        {
            float hc = hprev;
            g0 = fmaf(hc, Wh0[0], g0); G0 = fmaf(hc, Wh1[0], G0);
            hc = dpp_ror1(hc);
            g1 = fmaf(hc, Wh0[1], g1); G1 = fmaf(hc, Wh1[1], G1);
            hc = dpp_ror1(hc);
            g2 = fmaf(hc, Wh0[2], g2); G2 = fmaf(hc, Wh1[2], G2);
            hc = dpp_ror1(hc);
            g3 = fmaf(hc, Wh0[3], g3); G3 = fmaf(hc, Wh1[3], G3);
            hc = dpp_ror1(hc);
            g0 = fmaf(hc, Wh0[4], g0); G0 = fmaf(hc, Wh1[4], G0);
            hc = dpp_ror1(hc);
            g1 = fmaf(hc, Wh0[5], g1); G1 = fmaf(hc, Wh1[5], G1);
            hc = dpp_ror1(hc);
            g2 = fmaf(hc, Wh0[6], g2); G2 = fmaf(hc, Wh1[6], G2);
            hc = dpp_ror1(hc);
            g3 = fmaf(hc, Wh0[7], g3); G3 = fmaf(hc, Wh1[7], G3);
        }
        float glo = (g0 + g1) + (g2 + g3);
        float ghi = (G0 + G1) + (G2 + G3);

        // Activations: lo = sigmoid(i)/tanh(j) via lane consts; hi = sigmoid.
        float a_lo = fmaf(mK, frcp(1.0f + fexp2(sK * glo)), qK);
        float a_hi = frcp(1.0f + fexp2(-1.4426950408889634f * ghi));

        // Partner exchange: lane^8 within the row (involution).
        float p_lo = dpp_xor8(a_lo);
        float p_hi = dpp_xor8(a_hi);

        // i*j is a_lo*p_lo for BOTH halves; f/o need one select each.
        float fv = lowm ? a_hi : p_hi;
        float ov = lowm ? p_hi : a_hi;

        c = fmaf(c, fv, a_lo * p_lo);
        float th = fmaf(-2.0f,
                        frcp(1.0f + fexp2(2.8853900817779268f * c)),
                        1.0f);
        hprev = th * ov;
    }

    // Rebuild hall[0..7] within the 16-lane group: src=(lane&0x10)|j.
    float hall[NH];
    hall[0] = SWZ(hprev, 0x0010);
    hall[1] = SWZ(hprev, 0x0030);
    hall[2] = SWZ(hprev, 0x0050);
    hall[3] = SWZ(hprev, 0x0070);
    hall[4] = SWZ(hprev, 0x0090);
    hall[5] = SWZ(hprev, 0x00B0);
    hall[6] = SWZ(hprev, 0x00D0);
    hall[7] = SWZ(hprev, 0x00F0);

    if (m < NC) {
        float acc = bout[m];
#pragma unroll
        for (int k = 0; k < NH; ++k)
            acc = fmaf(hall[k], Wout[k * NC + m], acc);
        out[(size_t)e * NC + m] = acc;
    }
}

extern "C" void kernel_launch(void* const* d_in, const int* in_sizes, int n_in,
                              void* d_out, int out_size, void* d_ws, size_t ws_size,
                              hipStream_t stream) {
    const float* x    = (const float*)d_in[0];
    const float* W    = (const float*)d_in[1];
    const float* b    = (const float*)d_in[2];
    const float* Wout = (const float*)d_in[3];
    const float* bout = (const float*)d_in[4];
    float* out = (float*)d_out;

    const int B = in_sizes[0] / (TSTEPS * DIN);  // 32768
    const int grid = B / EPB;                    // 2048 blocks
    lstm_kernel<<<grid, 256, 0, stream>>>(x, W, b, Wout, bout, out);
}